// Round 1
// baseline (2259.572 us; speedup 1.0000x reference)
//
#include <hip/hip_runtime.h>

#define DEVINL __device__ __forceinline__

typedef unsigned int  uint32;
typedef unsigned short u16;

typedef short bf16x8  __attribute__((ext_vector_type(8)));
typedef float f32x16  __attribute__((ext_vector_type(16)));
typedef float fx2     __attribute__((ext_vector_type(2)));

union U4H { uint4 u; bf16x8 h; };

// ---------------- path tables (15 paths, enumeration order of reference) ----
// idx: 0:(0,0,0,0,F) 1:(0,1,1,0,F) 2:(0,2,2,0,F) 3:(1,0,1,0,F) 4:(1,1,2,0,F)
//      5:(1,1,0,1,F) 6:(1,1,1,0,T) 7:(1,2,1,1,F) 8:(1,2,2,0,T) 9:(2,0,2,0,F)
//     10:(2,1,1,1,F) 11:(2,1,2,0,T) 12:(2,2,2,1,F) 13:(2,2,0,2,F) 14:(2,2,1,1,T)
constexpr int PL1c[15] = {0,0,0,1,1,1,1,1,1,2,2,2,2,2,2};
constexpr int PL2c[15] = {0,1,2,0,1,1,1,2,2,0,1,1,2,2,2};
constexpr int PLOc[15] = {0,1,2,1,2,0,1,1,2,2,1,2,2,0,1};
constexpr int PTc [15] = {1,1,1,1,1,3,2,3,2,1,3,2,3,9,6};
constexpr int PW3c[3]  = {1,3,9};
constexpr int LOFFc[3] = {0,32,128};

// groups g = (s_out = g&1, Lout = g>>1); combos (path, s1, s2)
__device__ const int g_cnt[6] = {6,6,12,12,12,12};
__device__ const int g_off[6] = {0,6,12,24,36,48};
__device__ const int g_combo[60][3] = {
  // g0 (s=0,L=0)
  {0,0,0},{0,1,1},{5,0,0},{5,1,1},{13,0,0},{13,1,1},
  // g1 (s=1,L=0)
  {0,0,1},{0,1,0},{5,0,1},{5,1,0},{13,0,1},{13,1,0},
  // g2 (s=0,L=1)
  {1,0,0},{1,1,1},{3,0,0},{3,1,1},{7,0,0},{7,1,1},{10,0,0},{10,1,1},
  {6,0,1},{6,1,0},{14,0,1},{14,1,0},
  // g3 (s=1,L=1)
  {1,0,1},{1,1,0},{3,0,1},{3,1,0},{7,0,1},{7,1,0},{10,0,1},{10,1,0},
  {6,0,0},{6,1,1},{14,0,0},{14,1,1},
  // g4 (s=0,L=2)
  {2,0,0},{2,1,1},{4,0,0},{4,1,1},{9,0,0},{9,1,1},{12,0,0},{12,1,1},
  {8,0,1},{8,1,0},{11,0,1},{11,1,0},
  // g5 (s=1,L=2)
  {2,0,1},{2,1,0},{4,0,1},{4,1,0},{9,0,1},{9,1,0},{12,0,1},{12,1,0},
  {8,0,0},{8,1,1},{11,0,0},{11,1,1},
};

struct Terms { int iA[9]; int jB[9]; int sg[9]; };

DEVINL Terms make_terms(int path, int mo) {
  Terms t{};
  switch (path) {
    case 0:  t.iA[0]=0;  t.jB[0]=0;  t.sg[0]=1; break;
    case 1:  t.iA[0]=0;  t.jB[0]=mo; t.sg[0]=1; break;
    case 2:  t.iA[0]=0;  t.jB[0]=mo; t.sg[0]=1; break;
    case 3:  t.iA[0]=mo; t.jB[0]=0;  t.sg[0]=1; break;
    case 4:  t.iA[0]=mo/3; t.jB[0]=mo%3; t.sg[0]=1; break;
    case 5:  for (int v=0;v<3;++v){t.iA[v]=v; t.jB[v]=v; t.sg[v]=1;} break;
    case 6:  {int p=mo,u1=(p+1)%3,u2=(p+2)%3;
              t.iA[0]=u1; t.jB[0]=u2; t.sg[0]= 1;
              t.iA[1]=u2; t.jB[1]=u1; t.sg[1]=-1;} break;
    case 7:  {int x=mo; for(int u=0;u<3;++u){t.iA[u]=u; t.jB[u]=3*x+u; t.sg[u]=1;}} break;
    case 8:  {int x=mo/3,p=mo%3,u1=(p+1)%3,u2=(p+2)%3;
              t.iA[0]=u1; t.jB[0]=3*x+u2; t.sg[0]= 1;
              t.iA[1]=u2; t.jB[1]=3*x+u1; t.sg[1]=-1;} break;
    case 9:  t.iA[0]=mo; t.jB[0]=0; t.sg[0]=1; break;
    case 10: {int u=mo; for(int v=0;v<3;++v){t.iA[v]=3*u+v; t.jB[v]=v; t.sg[v]=1;}} break;
    case 11: {int u=mo/3,p=mo%3,v1=(p+1)%3,v2=(p+2)%3;
              t.iA[0]=3*u+v1; t.jB[0]=v2; t.sg[0]= 1;
              t.iA[1]=3*u+v2; t.jB[1]=v1; t.sg[1]=-1;} break;
    case 12: {int u=mo/3,x=mo%3; for(int v=0;v<3;++v){t.iA[v]=3*u+v; t.jB[v]=3*x+v; t.sg[v]=1;}} break;
    case 13: for (int w=0;w<9;++w){t.iA[w]=w; t.jB[w]=w; t.sg[w]=1;} break;
    case 14: {int p=mo,u1=(p+1)%3,u2=(p+2)%3;
              for(int v=0;v<3;++v){
                t.iA[2*v]  =3*u1+v; t.jB[2*v]  =3*u2+v; t.sg[2*v]  = 1;
                t.iA[2*v+1]=3*u2+v; t.jB[2*v+1]=3*u1+v; t.sg[2*v+1]=-1;}} break;
  }
  return t;
}

DEVINL u16 f2bf(float f) {            // RNE float->bf16
  uint32 u = __float_as_uint(f);
  u += 0x7fffu + ((u >> 16) & 1u);
  return (u16)(u >> 16);
}
DEVINL float bf2f(u16 h) { return __uint_as_float(((uint32)h) << 16); }

DEVINL void unpack8(uint4 r, int sg, fx2 out[4]) {
  uint32 s = (sg < 0) ? 0x80000000u : 0u;
  uint32 c[4] = {r.x, r.y, r.z, r.w};
#pragma unroll
  for (int q = 0; q < 4; ++q) {
    out[q].x = __uint_as_float(((c[q] << 16)) ^ s);
    out[q].y = __uint_as_float((c[q] & 0xffff0000u) ^ s);
  }
}

DEVINL bf16x8 packA(const fx2 p[4]) { // pack 8 f32 -> 8 bf16 (truncate), 1 v_perm per pair
  U4H r;
  r.u.x = __builtin_amdgcn_perm(__float_as_uint(p[0].y), __float_as_uint(p[0].x), 0x07060302u);
  r.u.y = __builtin_amdgcn_perm(__float_as_uint(p[1].y), __float_as_uint(p[1].x), 0x07060302u);
  r.u.z = __builtin_amdgcn_perm(__float_as_uint(p[2].y), __float_as_uint(p[2].x), 0x07060302u);
  r.u.w = __builtin_amdgcn_perm(__float_as_uint(p[3].y), __float_as_uint(p[3].x), 0x07060302u);
  return r.h;
}

DEVINL f32x16 mfma32(bf16x8 a, uint4 w, f32x16 c) {
  U4H x; x.u = w;
  return __builtin_amdgcn_mfma_f32_32x32x16_bf16(a, x.h, c, 0, 0, 0);
}

// ---------------- per-combo worker -----------------------------------------
template<int PATH>
DEVINL void run_combo(int s1, int s2, int n0,
                      const u16* __restrict__ x2t,
                      const u16* x1l, const uint4* wl,
                      f32x16* acc, int lane, int wv)
{
  constexpr int L1v = PL1c[PATH];
  constexpr int L2v = PL2c[PATH];
  constexpr int LOv = PLOc[PATH];
  constexpr int NT  = PW3c[LOv];
  constexpr int T   = PTc[PATH];
  constexpr int P1v = PW3c[L1v];
  constexpr bool BHO = (T > 6);          // register-save variant for P14 (T=9)
  const int a0   = wv * 4;               // this wave's 4 'a' channels (K-split)
  const int nloc = lane & 31;
  const int oct  = lane >> 5;
  // W fragments for my (a,bh) steps, resident across all tiles of this combo
  uint4 wf[4][2];
#pragma unroll
  for (int ia = 0; ia < 4; ++ia)
#pragma unroll
    for (int bh = 0; bh < 2; ++bh)
      wf[ia][bh] = wl[(((a0 + ia) * 2 + bh) << 6) + lane];
  const u16* bb = x2t + (size_t)(n0 + nloc) * 832 + s2 * 416 + LOFFc[L2v] + oct * 8;
  const u16* ab = x1l + nloc * 836 + s1 * 416 + LOFFc[L1v];
#pragma unroll
  for (int mo = 0; mo < NT; ++mo) {
    const Terms tm = make_terms(PATH, mo);
    if constexpr (!BHO) {
      fx2 b2[2][T][4];
#pragma unroll
      for (int bh = 0; bh < 2; ++bh)
#pragma unroll
        for (int tt = 0; tt < T; ++tt) {
          uint4 rv = *(const uint4*)(bb + tm.jB[tt] * 32 + bh * 16);
          unpack8(rv, tm.sg[tt], b2[bh][tt]);
        }
#pragma unroll
      for (int ia = 0; ia < 4; ++ia) {
        float av[T];
#pragma unroll
        for (int tt = 0; tt < T; ++tt)
          av[tt] = bf2f(ab[(a0 + ia) * P1v + tm.iA[tt]]);
#pragma unroll
        for (int bh = 0; bh < 2; ++bh) {
          fx2 p[4];
          { fx2 a2; a2.x = av[0]; a2.y = av[0];
#pragma unroll
            for (int q = 0; q < 4; ++q) p[q] = a2 * b2[bh][0][q]; }
#pragma unroll
          for (int tt = 1; tt < T; ++tt) {
            fx2 a2; a2.x = av[tt]; a2.y = av[tt];
#pragma unroll
            for (int q = 0; q < 4; ++q)
              p[q] = __builtin_elementwise_fma(a2, b2[bh][tt][q], p[q]);
          }
          acc[mo] = mfma32(packA(p), wf[ia][bh], acc[mo]);
        }
      }
    } else {
#pragma unroll
      for (int bh = 0; bh < 2; ++bh) {
        fx2 b2[T][4];
#pragma unroll
        for (int tt = 0; tt < T; ++tt) {
          uint4 rv = *(const uint4*)(bb + tm.jB[tt] * 32 + bh * 16);
          unpack8(rv, tm.sg[tt], b2[tt]);
        }
#pragma unroll
        for (int ia = 0; ia < 4; ++ia) {
          fx2 p[4];
          { float a0v = bf2f(ab[(a0 + ia) * P1v + tm.iA[0]]);
            fx2 a2; a2.x = a0v; a2.y = a0v;
#pragma unroll
            for (int q = 0; q < 4; ++q) p[q] = a2 * b2[0][q]; }
#pragma unroll
          for (int tt = 1; tt < T; ++tt) {
            float avt = bf2f(ab[(a0 + ia) * P1v + tm.iA[tt]]);
            fx2 a2; a2.x = avt; a2.y = avt;
#pragma unroll
            for (int q = 0; q < 4; ++q)
              p[q] = __builtin_elementwise_fma(a2, b2[tt][q], p[q]);
          }
          acc[0] = mfma32(packA(p), wf[ia][bh], acc[0]);
        }
      }
    }
  }
}

// ---------------- reduction + store ----------------------------------------
template<int NT>
DEVINL void reduce_store(const f32x16* acc, float* red, float* __restrict__ out,
                         int n0, int obase, int tid, int lane)
{
  const int col = lane & 31, oct = lane >> 5;
#pragma unroll
  for (int t = 0; t < NT; ++t)
#pragma unroll
    for (int r = 0; r < 16; ++r) {
      int row = (r & 3) + 8 * (r >> 2) + 4 * oct;   // m74/m101 C/D layout
      atomicAdd(&red[((t * 32 + row) << 5) + col], acc[t][r]);
    }
  __syncthreads();
  const int span = 32 * NT;
  for (int o = tid; o < 32 * span; o += 512) {
    int row = o / span; int c = o - row * span;
    int Z = c / NT;     int mo = c - Z * NT;
    out[(size_t)(n0 + row) * 832 + obase + c] = red[((mo * 32 + row) << 5) + Z];
  }
}

// ---------------- main kernel ----------------------------------------------
__global__ __launch_bounds__(512, 2) void k_main(
    const float* __restrict__ x1, const u16* __restrict__ x2t,
    const uint4* __restrict__ Wb, float* __restrict__ out)
{
  __shared__ u16   x1l[32 * 836];      // 53,504 B (row pad -> 2-way conflicts only)
  __shared__ uint4 wlds[4096];         // 65,536 B, one combo's swizzled W
  __shared__ float red[9216];          // 36,864 B cross-wave accumulator
  const int tid  = threadIdx.x;
  const int lane = tid & 63, wv = tid >> 6;
  const int n0   = blockIdx.x * 32;

  { // stage x1 rows -> bf16 LDS (once)
    int rr = tid >> 4, c0 = tid & 15;
    const float* src = x1 + (size_t)(n0 + rr) * 832;
#pragma unroll 4
    for (int jj = 0; jj < 52; ++jj) {
      int colx = c0 + jj * 16;
      x1l[rr * 836 + colx] = f2bf(src[colx]);
    }
  }

  f32x16 acc[9];
  for (int g = 0; g < 6; ++g) {
    const int s_out = g & 1;
    const int lout  = g >> 1;
    __syncthreads();                      // prior group done reading red
    for (int i = tid; i < 9216; i += 512) red[i] = 0.f;
#pragma unroll
    for (int t = 0; t < 9; ++t)
#pragma unroll
      for (int e = 0; e < 16; ++e) acc[t][e] = 0.f;

    const int cbase = g_off[g], cn = g_cnt[g];
    for (int ci = 0; ci < cn; ++ci) {
      const int path = g_combo[cbase + ci][0];
      const int s1   = g_combo[cbase + ci][1];
      const int s2   = g_combo[cbase + ci][2];
      const int pc   = path * 4 + s1 * 2 + s2;
      __syncthreads();                    // everyone done with previous Wlds
      { // stage this combo's 64KB W (pre-swizzled bf16) via async global->LDS
        const uint4* srcw = Wb + ((size_t)pc << 12);
#pragma unroll
        for (int it = 0; it < 8; ++it) {
          int idx = tid + it * 512;       // 4096 = 512*8 exact
          __builtin_amdgcn_global_load_lds(
              (const __attribute__((address_space(1))) unsigned int*)(srcw + idx),
              (__attribute__((address_space(3))) unsigned int*)(&wlds[idx]),
              16, 0, 0);
        }
      }
      __syncthreads();                    // barrier drains vmcnt -> W staged
      switch (path) {
        case 0:  run_combo<0 >(s1, s2, n0, x2t, x1l, wlds, acc, lane, wv); break;
        case 1:  run_combo<1 >(s1, s2, n0, x2t, x1l, wlds, acc, lane, wv); break;
        case 2:  run_combo<2 >(s1, s2, n0, x2t, x1l, wlds, acc, lane, wv); break;
        case 3:  run_combo<3 >(s1, s2, n0, x2t, x1l, wlds, acc, lane, wv); break;
        case 4:  run_combo<4 >(s1, s2, n0, x2t, x1l, wlds, acc, lane, wv); break;
        case 5:  run_combo<5 >(s1, s2, n0, x2t, x1l, wlds, acc, lane, wv); break;
        case 6:  run_combo<6 >(s1, s2, n0, x2t, x1l, wlds, acc, lane, wv); break;
        case 7:  run_combo<7 >(s1, s2, n0, x2t, x1l, wlds, acc, lane, wv); break;
        case 8:  run_combo<8 >(s1, s2, n0, x2t, x1l, wlds, acc, lane, wv); break;
        case 9:  run_combo<9 >(s1, s2, n0, x2t, x1l, wlds, acc, lane, wv); break;
        case 10: run_combo<10>(s1, s2, n0, x2t, x1l, wlds, acc, lane, wv); break;
        case 11: run_combo<11>(s1, s2, n0, x2t, x1l, wlds, acc, lane, wv); break;
        case 12: run_combo<12>(s1, s2, n0, x2t, x1l, wlds, acc, lane, wv); break;
        case 13: run_combo<13>(s1, s2, n0, x2t, x1l, wlds, acc, lane, wv); break;
        case 14: run_combo<14>(s1, s2, n0, x2t, x1l, wlds, acc, lane, wv); break;
      }
    }
    __syncthreads();                      // all waves' acc final
    const int obase = s_out * 416 + LOFFc[lout];
    if      (lout == 0) reduce_store<1>(acc, red, out, n0, obase, tid, lane);
    else if (lout == 1) reduce_store<3>(acc, red, out, n0, obase, tid, lane);
    else                reduce_store<9>(acc, red, out, n0, obase, tid, lane);
  }
}

// ---------------- pre-kernels ----------------------------------------------
// W -> bf16, swizzled into exact B-fragment lane order:
//   Wb[pc][a][bh][l][j] = bf16( w[pc*32768 + Z*1024 + a*32 + b] ),
//   Z = l&31, b = bh*16 + ((l>>5)&1)*8 + j
__global__ void k_convw(const float* __restrict__ w, u16* __restrict__ Wb) {
  int o  = blockIdx.x * 1024 + threadIdx.x;      // 1,966,080 total
  int j  = o & 7;
  int l  = (o >> 3) & 63;
  int bh = (o >> 9) & 1;
  int a  = (o >> 10) & 31;
  int pc = o >> 15;
  int Z  = l & 31;
  int b  = bh * 16 + ((l >> 5) & 1) * 8 + j;
  float f = w[((size_t)pc << 15) + (size_t)Z * 1024 + a * 32 + b];
  Wb[o] = f2bf(f);
}

// x2 -> bf16, transposed within each (s,L) block to [j][b] so 8 consecutive
// b-channels are one 16B load: x2t[n*832 + s*416 + Loff + j*32 + b]
__global__ void k_convx2(const float* __restrict__ x2, u16* __restrict__ x2t) {
  int o = blockIdx.x * 1024 + threadIdx.x;       // 6,815,744 total
  int n = o / 832; int r = o - n * 832;
  int s = (r >= 416); int r2 = r - s * 416;
  int L = (r2 >= 32) + (r2 >= 128);
  int off = (L == 0) ? 0 : ((L == 1) ? 32 : 128);
  int c = r2 - off;
  int j = c >> 5, b = c & 31;
  int p3 = (L == 0) ? 1 : ((L == 1) ? 3 : 9);
  float f = x2[(size_t)n * 832 + s * 416 + off + b * p3 + j];
  x2t[o] = f2bf(f);
}

// ---------------- launch ----------------------------------------------------
extern "C" void kernel_launch(void* const* d_in, const int* in_sizes, int n_in,
                              void* d_out, int out_size, void* d_ws, size_t ws_size,
                              hipStream_t stream) {
  const float* x1 = (const float*)d_in[0];
  const float* x2 = (const float*)d_in[1];
  const float* w  = (const float*)d_in[2];
  float* out = (float*)d_out;
  // ws layout: [0, 3.93MB) swizzled bf16 W ; [4MB, 4MB+13.6MB) bf16 x2t
  u16* Wb  = (u16*)d_ws;
  u16* x2t = (u16*)((char*)d_ws + (4u << 20));
  (void)in_sizes; (void)n_in; (void)out_size; (void)ws_size;

  k_convw <<<1920, 1024, 0, stream>>>(w, Wb);    // 1920*1024 = 1,966,080
  k_convx2<<<6656, 1024, 0, stream>>>(x2, x2t);  // 6656*1024 = 6,815,744
  k_main  <<<256, 512, 0, stream>>>(x1, x2t, (const uint4*)Wb, out);
}

// Round 2
// 1419.742 us; speedup vs baseline: 1.5915x; 1.5915x over previous
//
#include <hip/hip_runtime.h>

#define DEVINL __device__ __forceinline__

typedef unsigned int  uint32;
typedef unsigned short u16;

typedef short bf16x8  __attribute__((ext_vector_type(8)));
typedef float f32x16  __attribute__((ext_vector_type(16)));
typedef float fx2     __attribute__((ext_vector_type(2)));

union U4H { uint4 u; bf16x8 h; };

// ---------------- path tables (15 paths, enumeration order of reference) ----
// idx: 0:(0,0,0,0,F) 1:(0,1,1,0,F) 2:(0,2,2,0,F) 3:(1,0,1,0,F) 4:(1,1,2,0,F)
//      5:(1,1,0,1,F) 6:(1,1,1,0,T) 7:(1,2,1,1,F) 8:(1,2,2,0,T) 9:(2,0,2,0,F)
//     10:(2,1,1,1,F) 11:(2,1,2,0,T) 12:(2,2,2,1,F) 13:(2,2,0,2,F) 14:(2,2,1,1,T)
constexpr int PL1c[15] = {0,0,0,1,1,1,1,1,1,2,2,2,2,2,2};
constexpr int PL2c[15] = {0,1,2,0,1,1,1,2,2,0,1,1,2,2,2};
constexpr int PLOc[15] = {0,1,2,1,2,0,1,1,2,2,1,2,2,0,1};
constexpr int PTc [15] = {1,1,1,1,1,3,2,3,2,1,3,2,3,9,6};
constexpr int PW3c[3]  = {1,3,9};
constexpr int LOFFc[3] = {0,32,128};

// groups g = (s_out = g&1, Lout = g>>1); combos (path, s1, s2)
constexpr int GCNT[6] = {6,6,12,12,12,12};
constexpr int GNT [6] = {1,1,3,3,9,9};
constexpr int GCOMBO[6][12][3] = {
  {{0,0,0},{0,1,1},{5,0,0},{5,1,1},{13,0,0},{13,1,1},
   {0,0,0},{0,0,0},{0,0,0},{0,0,0},{0,0,0},{0,0,0}},
  {{0,0,1},{0,1,0},{5,0,1},{5,1,0},{13,0,1},{13,1,0},
   {0,0,0},{0,0,0},{0,0,0},{0,0,0},{0,0,0},{0,0,0}},
  {{1,0,0},{1,1,1},{3,0,0},{3,1,1},{7,0,0},{7,1,1},{10,0,0},{10,1,1},
   {6,0,1},{6,1,0},{14,0,1},{14,1,0}},
  {{1,0,1},{1,1,0},{3,0,1},{3,1,0},{7,0,1},{7,1,0},{10,0,1},{10,1,0},
   {6,0,0},{6,1,1},{14,0,0},{14,1,1}},
  {{2,0,0},{2,1,1},{4,0,0},{4,1,1},{9,0,0},{9,1,1},{12,0,0},{12,1,1},
   {8,0,1},{8,1,0},{11,0,1},{11,1,0}},
  {{2,0,1},{2,1,0},{4,0,1},{4,1,0},{9,0,1},{9,1,0},{12,0,1},{12,1,0},
   {8,0,0},{8,1,1},{11,0,0},{11,1,1}},
};

struct Terms { int iA[9]; int jB[9]; int sg[9]; };

DEVINL Terms make_terms(int path, int mo) {
  Terms t{};
  switch (path) {
    case 0:  t.iA[0]=0;  t.jB[0]=0;  t.sg[0]=1; break;
    case 1:  t.iA[0]=0;  t.jB[0]=mo; t.sg[0]=1; break;
    case 2:  t.iA[0]=0;  t.jB[0]=mo; t.sg[0]=1; break;
    case 3:  t.iA[0]=mo; t.jB[0]=0;  t.sg[0]=1; break;
    case 4:  t.iA[0]=mo/3; t.jB[0]=mo%3; t.sg[0]=1; break;
    case 5:  for (int v=0;v<3;++v){t.iA[v]=v; t.jB[v]=v; t.sg[v]=1;} break;
    case 6:  {int p=mo,u1=(p+1)%3,u2=(p+2)%3;
              t.iA[0]=u1; t.jB[0]=u2; t.sg[0]= 1;
              t.iA[1]=u2; t.jB[1]=u1; t.sg[1]=-1;} break;
    case 7:  {int x=mo; for(int u=0;u<3;++u){t.iA[u]=u; t.jB[u]=3*x+u; t.sg[u]=1;}} break;
    case 8:  {int x=mo/3,p=mo%3,u1=(p+1)%3,u2=(p+2)%3;
              t.iA[0]=u1; t.jB[0]=3*x+u2; t.sg[0]= 1;
              t.iA[1]=u2; t.jB[1]=3*x+u1; t.sg[1]=-1;} break;
    case 9:  t.iA[0]=mo; t.jB[0]=0; t.sg[0]=1; break;
    case 10: {int u=mo; for(int v=0;v<3;++v){t.iA[v]=3*u+v; t.jB[v]=v; t.sg[v]=1;}} break;
    case 11: {int u=mo/3,p=mo%3,v1=(p+1)%3,v2=(p+2)%3;
              t.iA[0]=3*u+v1; t.jB[0]=v2; t.sg[0]= 1;
              t.iA[1]=3*u+v2; t.jB[1]=v1; t.sg[1]=-1;} break;
    case 12: {int u=mo/3,x=mo%3; for(int v=0;v<3;++v){t.iA[v]=3*u+v; t.jB[v]=3*x+v; t.sg[v]=1;}} break;
    case 13: for (int w=0;w<9;++w){t.iA[w]=w; t.jB[w]=w; t.sg[w]=1;} break;
    case 14: {int p=mo,u1=(p+1)%3,u2=(p+2)%3;
              for(int v=0;v<3;++v){
                t.iA[2*v]  =3*u1+v; t.jB[2*v]  =3*u2+v; t.sg[2*v]  = 1;
                t.iA[2*v+1]=3*u2+v; t.jB[2*v+1]=3*u1+v; t.sg[2*v+1]=-1;}} break;
  }
  return t;
}

DEVINL u16 f2bf(float f) {            // RNE float->bf16
  uint32 u = __float_as_uint(f);
  u += 0x7fffu + ((u >> 16) & 1u);
  return (u16)(u >> 16);
}
DEVINL float bf2f(u16 h) { return __uint_as_float(((uint32)h) << 16); }

DEVINL void unpack8(uint4 r, fx2 out[4]) {   // no sign: applied to A scalar
  uint32 c[4] = {r.x, r.y, r.z, r.w};
#pragma unroll
  for (int q = 0; q < 4; ++q) {
    out[q].x = __uint_as_float(c[q] << 16);
    out[q].y = __uint_as_float(c[q] & 0xffff0000u);
  }
}

DEVINL bf16x8 packA(const fx2 p[4]) { // pack 8 f32 -> 8 bf16 (truncate), 1 v_perm per pair
  U4H r;
  r.u.x = __builtin_amdgcn_perm(__float_as_uint(p[0].y), __float_as_uint(p[0].x), 0x07060302u);
  r.u.y = __builtin_amdgcn_perm(__float_as_uint(p[1].y), __float_as_uint(p[1].x), 0x07060302u);
  r.u.z = __builtin_amdgcn_perm(__float_as_uint(p[2].y), __float_as_uint(p[2].x), 0x07060302u);
  r.u.w = __builtin_amdgcn_perm(__float_as_uint(p[3].y), __float_as_uint(p[3].x), 0x07060302u);
  return r.h;
}

DEVINL f32x16 mfma32(bf16x8 a, uint4 w, f32x16 c) {
  U4H x; x.u = w;
  return __builtin_amdgcn_mfma_f32_32x32x16_bf16(a, x.h, c, 0, 0, 0);
}

// ---------------- per-combo worker -----------------------------------------
// Wave split: bh = wv&1 (which 16-b half), a0 = (wv>>1)*8 (8 'a' channels).
// Per tile each wave issues 8 mfmas; 8 waves cover K = 32a x 32b = 1024.
template<int PATH, int NT>
DEVINL void run_combo(int s1, int s2, int n0,
                      const u16* __restrict__ x2t,
                      const u16* x1l, const uint4* wl,
                      f32x16* acc, int lane, int wv)
{
  constexpr int L1v = PL1c[PATH];
  constexpr int L2v = PL2c[PATH];
  constexpr int T   = PTc[PATH];
  constexpr int P1v = PW3c[L1v];
  const int bh   = wv & 1;
  const int a0   = (wv >> 1) * 8;
  const int nloc = lane & 31;
  const int oct  = lane >> 5;
  // W fragments for my (a, bh) steps, resident across all tiles of this combo
  uint4 wf[8];
#pragma unroll
  for (int ia = 0; ia < 8; ++ia)
    wf[ia] = wl[(((a0 + ia) * 2 + bh) << 6) + lane];
  const u16* bb = x2t + (size_t)(n0 + nloc) * 832 + s2 * 416 + LOFFc[L2v]
                + bh * 16 + oct * 8;
  const u16* ab = x1l + nloc * 836 + s1 * 416 + LOFFc[L1v];
#pragma unroll
  for (int mo = 0; mo < NT; ++mo) {
    const Terms tm = make_terms(PATH, mo);
    fx2 b2[T][4];
#pragma unroll
    for (int tt = 0; tt < T; ++tt) {
      uint4 rv = *(const uint4*)(bb + tm.jB[tt] * 32);
      unpack8(rv, b2[tt]);
    }
#pragma unroll
    for (int ia = 0; ia < 8; ++ia) {
      fx2 p[4];
      {
        float av = bf2f(ab[(a0 + ia) * P1v + tm.iA[0]]);
        if (tm.sg[0] < 0) av = -av;
        fx2 a2; a2.x = av; a2.y = av;
#pragma unroll
        for (int q = 0; q < 4; ++q) p[q] = a2 * b2[0][q];
      }
#pragma unroll
      for (int tt = 1; tt < T; ++tt) {
        float av = bf2f(ab[(a0 + ia) * P1v + tm.iA[tt]]);
        if (tm.sg[tt] < 0) av = -av;
        fx2 a2; a2.x = av; a2.y = av;
#pragma unroll
        for (int q = 0; q < 4; ++q)
          p[q] = __builtin_elementwise_fma(a2, b2[tt][q], p[q]);
      }
      acc[mo] = mfma32(packA(p), wf[ia], acc[mo]);
    }
  }
}

// ---------------- group processing (NT statically sized!) -------------------
template<int G>
DEVINL void process_group(int n0, const u16* __restrict__ x2t,
                          const u16* x1l, const uint4* wlds, const uint4* Wb,
                          float* red, float* __restrict__ out,
                          int tid, int lane, int wv)
{
  constexpr int NT   = GNT[G];
  constexpr int s_out = G & 1;
  constexpr int lout  = G >> 1;
  __syncthreads();                       // prior group done reading red
  for (int i = tid; i < 1024 * NT; i += 512) red[i] = 0.f;
  f32x16 acc[NT];
#pragma unroll
  for (int t = 0; t < NT; ++t)
#pragma unroll
    for (int e = 0; e < 16; ++e) acc[t][e] = 0.f;

  for (int ci = 0; ci < GCNT[G]; ++ci) {
    const int path = GCOMBO[G][ci][0];
    const int s1   = GCOMBO[G][ci][1];
    const int s2   = GCOMBO[G][ci][2];
    const int pc   = path * 4 + s1 * 2 + s2;
    __syncthreads();                     // everyone done with previous Wlds
    {
      const uint4* srcw = Wb + ((size_t)pc << 12);
#pragma unroll
      for (int it = 0; it < 8; ++it) {
        int idx = tid + it * 512;        // 4096 = 512*8 exact
        __builtin_amdgcn_global_load_lds(
            (const __attribute__((address_space(1))) unsigned int*)(srcw + idx),
            (__attribute__((address_space(3))) unsigned int*)(&wlds[idx]),
            16, 0, 0);
      }
    }
    __syncthreads();                     // barrier drains vmcnt -> W staged
    switch (path) {
      case 0:  run_combo<0 ,NT>(s1,s2,n0,x2t,x1l,wlds,acc,lane,wv); break;
      case 1:  run_combo<1 ,NT>(s1,s2,n0,x2t,x1l,wlds,acc,lane,wv); break;
      case 2:  run_combo<2 ,NT>(s1,s2,n0,x2t,x1l,wlds,acc,lane,wv); break;
      case 3:  run_combo<3 ,NT>(s1,s2,n0,x2t,x1l,wlds,acc,lane,wv); break;
      case 4:  run_combo<4 ,NT>(s1,s2,n0,x2t,x1l,wlds,acc,lane,wv); break;
      case 5:  run_combo<5 ,NT>(s1,s2,n0,x2t,x1l,wlds,acc,lane,wv); break;
      case 6:  run_combo<6 ,NT>(s1,s2,n0,x2t,x1l,wlds,acc,lane,wv); break;
      case 7:  run_combo<7 ,NT>(s1,s2,n0,x2t,x1l,wlds,acc,lane,wv); break;
      case 8:  run_combo<8 ,NT>(s1,s2,n0,x2t,x1l,wlds,acc,lane,wv); break;
      case 9:  run_combo<9 ,NT>(s1,s2,n0,x2t,x1l,wlds,acc,lane,wv); break;
      case 10: run_combo<10,NT>(s1,s2,n0,x2t,x1l,wlds,acc,lane,wv); break;
      case 11: run_combo<11,NT>(s1,s2,n0,x2t,x1l,wlds,acc,lane,wv); break;
      case 12: run_combo<12,NT>(s1,s2,n0,x2t,x1l,wlds,acc,lane,wv); break;
      case 13: run_combo<13,NT>(s1,s2,n0,x2t,x1l,wlds,acc,lane,wv); break;
      case 14: run_combo<14,NT>(s1,s2,n0,x2t,x1l,wlds,acc,lane,wv); break;
    }
  }
  __syncthreads();                       // all waves' acc final
  // cross-wave combine in LDS, then store
  const int col = lane & 31, oct = lane >> 5;
#pragma unroll
  for (int t = 0; t < NT; ++t)
#pragma unroll
    for (int r = 0; r < 16; ++r) {
      int row = (r & 3) + 8 * (r >> 2) + 4 * oct;   // m74/m101 C/D layout
      atomicAdd(&red[((t * 32 + row) << 5) + col], acc[t][r]);
    }
  __syncthreads();
  constexpr int obase = s_out * 416 + LOFFc[lout];
  constexpr int span  = 32 * NT;
  for (int o = tid; o < 32 * span; o += 512) {
    int row = o / span; int c = o - row * span;
    int Z = c / NT;     int mo = c - Z * NT;
    out[(size_t)(n0 + row) * 832 + obase + c] = red[((mo * 32 + row) << 5) + Z];
  }
}

// ---------------- main kernel ----------------------------------------------
// LDS 153.5KB -> 1 block/CU, 8 waves = 2 waves/SIMD. waves_per_eu(2,2) pins
// the allocator to the full 256-reg budget (R1: min-only bound -> 128 VGPR ->
// acc spill -> 9GB scratch traffic).
__global__ __attribute__((amdgpu_flat_work_group_size(512,512),
                          amdgpu_waves_per_eu(2,2)))
void k_main(const float* __restrict__ x1, const u16* __restrict__ x2t,
            const uint4* __restrict__ Wb, float* __restrict__ out)
{
  __shared__ u16   x1l[32 * 836];      // 53,504 B (pad 836: stride%32=2 -> free)
  __shared__ uint4 wlds[4096];         // 65,536 B, one combo's swizzled W
  __shared__ float red[9216];          // 36,864 B cross-wave accumulator
  const int tid  = threadIdx.x;
  const int lane = tid & 63, wv = tid >> 6;
  const int n0   = blockIdx.x * 32;

  { // stage x1 rows -> bf16 LDS (once)
    int rr = tid >> 4, c0 = tid & 15;
    const float* src = x1 + (size_t)(n0 + rr) * 832;
#pragma unroll 4
    for (int jj = 0; jj < 52; ++jj) {
      int colx = c0 + jj * 16;
      x1l[rr * 836 + colx] = f2bf(src[colx]);
    }
  }

  process_group<0>(n0, x2t, x1l, wlds, Wb, red, out, tid, lane, wv);
  process_group<1>(n0, x2t, x1l, wlds, Wb, red, out, tid, lane, wv);
  process_group<2>(n0, x2t, x1l, wlds, Wb, red, out, tid, lane, wv);
  process_group<3>(n0, x2t, x1l, wlds, Wb, red, out, tid, lane, wv);
  process_group<4>(n0, x2t, x1l, wlds, Wb, red, out, tid, lane, wv);
  process_group<5>(n0, x2t, x1l, wlds, Wb, red, out, tid, lane, wv);
}

// ---------------- pre-kernels ----------------------------------------------
// W -> bf16, swizzled into exact B-fragment lane order:
//   Wb[pc][a][bh][l][j] = bf16( w[pc*32768 + Z*1024 + a*32 + b] ),
//   Z = l&31, b = bh*16 + ((l>>5)&1)*8 + j
__global__ void k_convw(const float* __restrict__ w, u16* __restrict__ Wb) {
  int o  = blockIdx.x * 1024 + threadIdx.x;      // 1,966,080 total
  int j  = o & 7;
  int l  = (o >> 3) & 63;
  int bh = (o >> 9) & 1;
  int a  = (o >> 10) & 31;
  int pc = o >> 15;
  int Z  = l & 31;
  int b  = bh * 16 + ((l >> 5) & 1) * 8 + j;
  float f = w[((size_t)pc << 15) + (size_t)Z * 1024 + a * 32 + b];
  Wb[o] = f2bf(f);
}

// x2 -> bf16, transposed within each (s,L) block to [j][b] so 8 consecutive
// b-channels are one 16B load: x2t[n*832 + s*416 + Loff + j*32 + b]
__global__ void k_convx2(const float* __restrict__ x2, u16* __restrict__ x2t) {
  int o = blockIdx.x * 1024 + threadIdx.x;       // 6,815,744 total
  int n = o / 832; int r = o - n * 832;
  int s = (r >= 416); int r2 = r - s * 416;
  int L = (r2 >= 32) + (r2 >= 128);
  int off = (L == 0) ? 0 : ((L == 1) ? 32 : 128);
  int c = r2 - off;
  int j = c >> 5, b = c & 31;
  int p3 = (L == 0) ? 1 : ((L == 1) ? 3 : 9);
  float f = x2[(size_t)n * 832 + s * 416 + off + b * p3 + j];
  x2t[o] = f2bf(f);
}

// ---------------- launch ----------------------------------------------------
extern "C" void kernel_launch(void* const* d_in, const int* in_sizes, int n_in,
                              void* d_out, int out_size, void* d_ws, size_t ws_size,
                              hipStream_t stream) {
  const float* x1 = (const float*)d_in[0];
  const float* x2 = (const float*)d_in[1];
  const float* w  = (const float*)d_in[2];
  float* out = (float*)d_out;
  // ws layout: [0, 3.93MB) swizzled bf16 W ; [4MB, 4MB+13.6MB) bf16 x2t
  u16* Wb  = (u16*)d_ws;
  u16* x2t = (u16*)((char*)d_ws + (4u << 20));
  (void)in_sizes; (void)n_in; (void)out_size; (void)ws_size;

  k_convw <<<1920, 1024, 0, stream>>>(w, Wb);    // 1920*1024 = 1,966,080
  k_convx2<<<6656, 1024, 0, stream>>>(x2, x2t);  // 6656*1024 = 6,815,744
  k_main  <<<256, 512, 0, stream>>>(x1, x2t, (const uint4*)Wb, out);
}